// Round 2
// baseline (4795.818 us; speedup 1.0000x reference)
//
#include <hip/hip_runtime.h>

#define TT 2048
#define BB 512
#define II 5
#define HH 64

__device__ __forceinline__ float sigm(float v)   { return 1.0f / (1.0f + __expf(-v)); }
__device__ __forceinline__ float tanh_f(float v) { return 1.0f - 2.0f / (1.0f + __expf(2.0f * v)); }

// Keep a value opaque so the compiler cannot rematerialize it from memory:
#define KEEP(v) asm volatile("" : "+v"(v))

__global__ __launch_bounds__(256, 2) void lstm2_kernel(
    const float* __restrict__ x,
    const float* __restrict__ W_ih0, const float* __restrict__ W_hh0,
    const float* __restrict__ b_ih0, const float* __restrict__ b_hh0,
    const float* __restrict__ W_ih1, const float* __restrict__ W_hh1,
    const float* __restrict__ b_ih1, const float* __restrict__ b_hh1,
    const float* __restrict__ W_out, const float* __restrict__ b_out,
    float* __restrict__ out)
{
    const int t = threadIdx.x;      // gate row 0..255
    const int b = blockIdx.x;       // batch element
    const int gate = t >> 6;        // 0=i 1=f 2=g 3=o

    __shared__ __align__(16) float act[256];
    __shared__ __align__(16) float h1s[HH];
    __shared__ __align__(16) float h2s[HH];

    // ---- load this row's weights into registers, force residency ----
    float wih0[II];
    #pragma unroll
    for (int k = 0; k < II; ++k) { wih0[k] = W_ih0[t * II + k]; }
    const float bias0 = b_ih0[t] + b_hh0[t];
    const float bias1 = b_ih1[t] + b_hh1[t];

    float4 whh0[16], wih1[16], whh1[16];
    {
        const float4* p0 = (const float4*)(W_hh0 + t * HH);
        const float4* p1 = (const float4*)(W_ih1 + t * HH);
        const float4* p2 = (const float4*)(W_hh1 + t * HH);
        #pragma unroll
        for (int k = 0; k < 16; ++k) { whh0[k] = p0[k]; wih1[k] = p1[k]; whh1[k] = p2[k]; }
    }
    #pragma unroll
    for (int k = 0; k < 16; ++k) {
        KEEP(whh0[k].x); KEEP(whh0[k].y); KEEP(whh0[k].z); KEEP(whh0[k].w);
        KEEP(wih1[k].x); KEEP(wih1[k].y); KEEP(wih1[k].z); KEEP(wih1[k].w);
        KEEP(whh1[k].x); KEEP(whh1[k].y); KEEP(whh1[k].z); KEEP(whh1[k].w);
    }
    #pragma unroll
    for (int k = 0; k < II; ++k) { KEEP(wih0[k]); }

    float c1 = 0.0f, c2 = 0.0f;
    if (t < HH) { h1s[t] = 0.0f; h2s[t] = 0.0f; }
    __syncthreads();

    const float* xb = x + b * II;   // x[(step*BB + b)*II + k]

    // acc_pre for step 0: bias0 + Wih0 . x[0]
    float accpre = bias0;
    #pragma unroll
    for (int k = 0; k < II; ++k) accpre = fmaf(xb[k], wih0[k], accpre);

    for (int step = 0; step < TT; ++step) {
        // ---- layer-1 partial (h2s from prev step is stable here) ----
        float acc2 = bias1;
        #pragma unroll
        for (int k = 0; k < 16; ++k) {
            float4 h = ((const float4*)h2s)[k];
            acc2 = fmaf(h.x, whh1[k].x, acc2);
            acc2 = fmaf(h.y, whh1[k].y, acc2);
            acc2 = fmaf(h.z, whh1[k].z, acc2);
            acc2 = fmaf(h.w, whh1[k].w, acc2);
        }

        // ---- layer-0 gates: accpre + Whh0 . h1_prev ----
        float acc = accpre;
        #pragma unroll
        for (int k = 0; k < 16; ++k) {
            float4 h = ((const float4*)h1s)[k];
            acc = fmaf(h.x, whh0[k].x, acc);
            acc = fmaf(h.y, whh0[k].y, acc);
            acc = fmaf(h.z, whh0[k].z, acc);
            acc = fmaf(h.w, whh0[k].w, acc);
        }
        act[t] = (gate == 2) ? tanh_f(acc) : sigm(acc);
        __syncthreads();                        // A: act(layer0) ready

        if (t < HH) {                           // layer-0 state update (wave 0)
            float iv = act[t], fv = act[HH + t], gv = act[2 * HH + t], ov = act[3 * HH + t];
            c1 = fv * c1 + iv * gv;
            h1s[t] = ov * tanh_f(c1);
        }
        __syncthreads();                        // B: h1s ready, act free

        // ---- layer-1 gates finish: + Wih1 . h1_new ----
        #pragma unroll
        for (int k = 0; k < 16; ++k) {
            float4 h = ((const float4*)h1s)[k];
            acc2 = fmaf(h.x, wih1[k].x, acc2);
            acc2 = fmaf(h.y, wih1[k].y, acc2);
            acc2 = fmaf(h.z, wih1[k].z, acc2);
            acc2 = fmaf(h.w, wih1[k].w, acc2);
        }
        act[t] = (gate == 2) ? tanh_f(acc2) : sigm(acc2);

        // fill the span: next step's x partial (wave-uniform loads)
        {
            int s2 = (step + 1 < TT) ? (step + 1) : (TT - 1);
            const float* xnp = xb + (size_t)s2 * (BB * II);
            float ap = bias0;
            #pragma unroll
            for (int k = 0; k < II; ++k) ap = fmaf(xnp[k], wih0[k], ap);
            accpre = ap;
        }
        __syncthreads();                        // C: act(layer1) ready

        if (t < HH) {                           // layer-1 state update (wave 0)
            float iv = act[t], fv = act[HH + t], gv = act[2 * HH + t], ov = act[3 * HH + t];
            c2 = fv * c2 + iv * gv;
            h2s[t] = ov * tanh_f(c2);
        }
        __syncthreads();                        // D: h2s ready
    }

    // ---- final projection: out[b] = h2 . W_out + b_out ----
    if (t < HH) {
        float v = h2s[t] * W_out[t];
        #pragma unroll
        for (int off = 32; off > 0; off >>= 1) v += __shfl_xor(v, off);
        if (t == 0) out[b] = v + b_out[0];
    }
}

extern "C" void kernel_launch(void* const* d_in, const int* in_sizes, int n_in,
                              void* d_out, int out_size, void* d_ws, size_t ws_size,
                              hipStream_t stream) {
    const float* x     = (const float*)d_in[0];
    const float* W_ih0 = (const float*)d_in[1];
    const float* W_hh0 = (const float*)d_in[2];
    const float* b_ih0 = (const float*)d_in[3];
    const float* b_hh0 = (const float*)d_in[4];
    const float* W_ih1 = (const float*)d_in[5];
    const float* W_hh1 = (const float*)d_in[6];
    const float* b_ih1 = (const float*)d_in[7];
    const float* b_hh1 = (const float*)d_in[8];
    const float* W_out = (const float*)d_in[9];
    const float* b_out = (const float*)d_in[10];
    float* out = (float*)d_out;

    lstm2_kernel<<<dim3(BB), dim3(256), 0, stream>>>(
        x, W_ih0, W_hh0, b_ih0, b_hh0, W_ih1, W_hh1, b_ih1, b_hh1, W_out, b_out, out);
}